// Round 16
// baseline (555.673 us; speedup 1.0000x reference)
//
#include <hip/hip_runtime.h>
#include <hip/hip_bf16.h>
#include <stdint.h>

#define NN 8192
#define FD 690
#define NH 3
#define KPAD 704   // F_IN padded to mult of 64
#define OPAD 768   // F_OUT padded to mult of 128 (row FD holds constant 1 -> Z column)
#define USTRIDE 704
#define KS 2       // K-split factor for k_pv
#define GW_BLOCKS 576   // gemm_wht blocks in the fused kernel
#define PK_BLOCKS 1024  // pack blocks in the fused kernel (32 tasks/wave)
#define LOG2E 1.4426950408889634f

typedef __attribute__((ext_vector_type(8))) short bf16x8;
typedef __attribute__((ext_vector_type(4))) float f32x4;

typedef __attribute__((address_space(1))) const void gas_t;
typedef __attribute__((address_space(3))) void las_t;

__device__ __forceinline__ void async_ld16(const void* g, void* l) {
  __builtin_amdgcn_global_load_lds((gas_t*)g, (las_t*)l, 16, 0, 0);
}

__device__ __forceinline__ float bf2f(unsigned short u) {
  return __uint_as_float(((unsigned int)u) << 16);
}
__device__ __forceinline__ unsigned short f2bf(float f) {
  __hip_bfloat16 h = __float2bfloat16(f);
  return *reinterpret_cast<unsigned short*>(&h);
}
// r = bit[lane] of (hi:lo) ? e : 0 — mask forced scalar via readfirstlane upstream
__device__ __forceinline__ float selbit(float e, uint32_t lo, uint32_t hi) {
  uint64_t m = ((uint64_t)hi << 32) | lo;
  float r;
  asm("v_cndmask_b32 %0, 0, %1, %2" : "=v"(r) : "v"(e), "s"(m));
  return r;
}

// ---------- fused cast / pad / zero-acc (xb vec4, wt scalar, acc zeroing) ----------
__global__ __launch_bounds__(256) void k_cast(const float* __restrict__ x,
                                              const float* __restrict__ W,
                                              unsigned short* __restrict__ xb,
                                              unsigned short* __restrict__ wt,
                                              float4* __restrict__ accz) {
  int q = blockIdx.x * 256 + threadIdx.x;
  const int XQ = NN * KPAD / 4;
  if (q < XQ) {
    int idx = q * 4;
    int n = idx / KPAD, f = idx - n * KPAD;   // f mult of 4
    uint2 out;
    if (f + 3 < FD) {
      const float* xp = &x[(size_t)n * FD + f];
      float2 a = *reinterpret_cast<const float2*>(xp);
      float2 b = *reinterpret_cast<const float2*>(xp + 2);
      out.x = (uint32_t)f2bf(a.x) | ((uint32_t)f2bf(a.y) << 16);
      out.y = (uint32_t)f2bf(b.x) | ((uint32_t)f2bf(b.y) << 16);
    } else {
      unsigned short e[4];
#pragma unroll
      for (int t = 0; t < 4; ++t) {
        int ff = f + t;
        e[t] = (ff < FD) ? f2bf(x[(size_t)n * FD + ff]) : 0;
      }
      out.x = (uint32_t)e[0] | ((uint32_t)e[1] << 16);
      out.y = (uint32_t)e[2] | ((uint32_t)e[3] << 16);
    }
    *reinterpret_cast<uint2*>(&xb[idx]) = out;
    return;
  }
  int idx = q - XQ;
  if (idx < NH * OPAD * KPAD) {
    int h = idx / (OPAD * KPAD);
    int rem = idx - h * OPAD * KPAD;
    int o = rem / KPAD, f = rem - o * KPAD;
    float v = (o < FD && f < FD) ? W[((size_t)h * FD + f) * FD + o] : 0.f;
    wt[idx] = f2bf(v);
    return;
  }
  idx -= NH * OPAD * KPAD;
  if (idx < 2 * NH * NN / 4) {
    float4 z; z.x = 0.f; z.y = 0.f; z.z = 0.f; z.w = 0.f;
    accz[idx] = z;
  }
}

// ---------- FUSED: gemm_wht (blocks < GW_BLOCKS) + adjacency pack (rest) ----------
// Pack overlaps on HBM pipe while gemm runs MFMA/LDS (independent work).
__global__ __launch_bounds__(512) void k_gw_pack(const unsigned short* __restrict__ wt,
                                                 const unsigned short* __restrict__ xb,
                                                 const float* __restrict__ a,
                                                 unsigned short* __restrict__ wht,
                                                 float* __restrict__ a1acc,
                                                 float* __restrict__ a2acc,
                                                 const int4* __restrict__ adj4,
                                                 uint64_t* __restrict__ bm) {
  __shared__ unsigned short As[128 * 64];
  __shared__ unsigned short Bs[256 * 64];
  const int tid = threadIdx.x;
  if (blockIdx.x >= GW_BLOCKS) {
    // ---- pack: int4 loads + shfl nibble tree; 32 tasks per wave ----
    const int pid = blockIdx.x - GW_BLOCKS;
    const int lane = tid & 63;
    int task = pid * 8 + (tid >> 6);          // wave-task base
    for (int t = 0; t < 32; ++t, task += PK_BLOCKS * 8) {
      int i = task >> 5, seg = task & 31;
      int4 v = adj4[(size_t)i * (NN / 4) + seg * 64 + lane];
      uint32_t nib = (uint32_t)(v.x > 0) | ((uint32_t)(v.y > 0) << 1)
                   | ((uint32_t)(v.z > 0) << 2) | ((uint32_t)(v.w > 0) << 3);
      nib |= __shfl_xor(nib, 1) << 4;
      nib |= __shfl_xor(nib, 2) << 8;
      nib |= __shfl_xor(nib, 4) << 16;
      uint32_t hi = __shfl_xor(nib, 8);
      if ((lane & 15) == 0)
        bm[(size_t)i * 128 + seg * 4 + (lane >> 4)] = (uint64_t)nib | ((uint64_t)hi << 32);
    }
    return;
  }
  // ---- gemm_wht: WhT[h][o][n] = sum_f x[n][f] W[h][f][o] (bf16; row FD = 1.0) ----
  const int bx = blockIdx.x;
  const int m0 = (bx % 6) * 128;            // o
  const int n0 = ((bx / 6) % 32) * 256;     // node
  const int h  = bx / 192;
  const int w = tid >> 6, l = tid & 63;
  const int wm = w >> 2, wn = w & 3;
  const unsigned short* Ag = wt + (size_t)h * OPAD * KPAD;
  f32x4 acc[4][4] = {};
  for (int kt = 0; kt < KPAD / 64; ++kt) {
    const int k0 = kt * 64;
#pragma unroll
    for (int r = 0; r < 2; ++r) {
      const unsigned short* g = Ag + (size_t)(m0 + r * 64 + w * 8 + (l >> 3)) * KPAD + k0 + (l & 7) * 8;
      async_ld16(g, &As[(r * 64 + w * 8) * 64]);
    }
#pragma unroll
    for (int r = 0; r < 4; ++r) {
      const unsigned short* g = xb + (size_t)(n0 + r * 64 + w * 8 + (l >> 3)) * KPAD + k0 + (l & 7) * 8;
      async_ld16(g, &Bs[(r * 64 + w * 8) * 64]);
    }
    __syncthreads();
#pragma unroll
    for (int ks = 0; ks < 2; ++ks) {
      bf16x8 af[4], bfr[4];
#pragma unroll
      for (int mi = 0; mi < 4; ++mi)
        af[mi] = *reinterpret_cast<const bf16x8*>(
            &As[(wm * 64 + mi * 16 + (l & 15)) * 64 + ks * 32 + (l >> 4) * 8]);
#pragma unroll
      for (int ni = 0; ni < 4; ++ni)
        bfr[ni] = *reinterpret_cast<const bf16x8*>(
            &Bs[(wn * 64 + ni * 16 + (l & 15)) * 64 + ks * 32 + (l >> 4) * 8]);
#pragma unroll
      for (int mi = 0; mi < 4; ++mi)
#pragma unroll
        for (int ni = 0; ni < 4; ++ni)
          acc[mi][ni] = __builtin_amdgcn_mfma_f32_16x16x32_bf16(af[mi], bfr[ni], acc[mi][ni], 0, 0, 0);
    }
    __syncthreads();
  }
  unsigned short* Wh = wht + (size_t)h * OPAD * NN;
#pragma unroll
  for (int mi = 0; mi < 4; ++mi)
#pragma unroll
    for (int j = 0; j < 4; ++j) {
      int o = m0 + wm * 64 + mi * 16 + (l >> 4) * 4 + j;
#pragma unroll
      for (int ni = 0; ni < 4; ++ni) {
        int n = n0 + wn * 64 + ni * 16 + (l & 15);
        float val = (o == FD) ? 1.0f : acc[mi][ni][j];  // pad rows are exactly 0; row FD = ones
        Wh[(size_t)o * NN + n] = f2bf(val);
      }
    }
  // ---- a1/a2 partial projections (f32 acc, per-(n) atomics) ----
  const float* ap1 = a + h * 2 * FD;
  const float* ap2 = ap1 + FD;
  float av1[4][4], av2[4][4];
#pragma unroll
  for (int mi = 0; mi < 4; ++mi)
#pragma unroll
    for (int j = 0; j < 4; ++j) {
      int o = m0 + wm * 64 + mi * 16 + (l >> 4) * 4 + j;
      bool ok = (o < FD);
      av1[mi][j] = ok ? ap1[o] : 0.f;
      av2[mi][j] = ok ? ap2[o] : 0.f;
    }
#pragma unroll
  for (int ni = 0; ni < 4; ++ni) {
    float p1 = 0.f, p2 = 0.f;
#pragma unroll
    for (int mi = 0; mi < 4; ++mi)
#pragma unroll
      for (int j = 0; j < 4; ++j) {
        p1 += acc[mi][ni][j] * av1[mi][j];
        p2 += acc[mi][ni][j] * av2[mi][j];
      }
    int n = n0 + wn * 64 + ni * 16 + (l & 15);
    unsafeAtomicAdd(&a1acc[h * NN + n], p1);
    unsafeAtomicAdd(&a2acc[h * NN + n], p2);
  }
}

// ---------- E/F factors from accumulated a1/a2 ----------
__global__ __launch_bounds__(256) void k_exp(const float* __restrict__ a1acc,
                                             const float* __restrict__ a2acc,
                                             float* __restrict__ e1s, float* __restrict__ f1s,
                                             float* __restrict__ e2s, float* __restrict__ f2s) {
  int i = blockIdx.x * 256 + threadIdx.x;
  if (i >= NH * NN) return;
  float s1 = a1acc[i] * LOG2E, s2 = a2acc[i] * LOG2E;
  e1s[i] = exp2f(s1);
  f1s[i] = exp2f(0.2f * s1);
  e2s[i] = exp2f(s2);
  f2s[i] = exp2f(0.2f * s2);
}

// ---------- PV: U{0,1}[h][i][n] (+)= sum_{j in kseg} w_ij WhT[n][j] ; column FD = Z ----------
// w_ij = max(E1_i*E2_j, F1_i*F2_j)  (== exp2(log2e*lrelu(a1_i+a2_j)), exp2 monotone)
// r7 measured-optimum loop (370us, VGPR 56, 0 bank conflicts), untouched.
__global__ __launch_bounds__(512, 4) void k_pv(const unsigned short* __restrict__ wht,
                                               const float* __restrict__ e1s,
                                               const float* __restrict__ f1s,
                                               const float* __restrict__ e2s,
                                               const float* __restrict__ f2s,
                                               const uint64_t* __restrict__ bm,
                                               float* __restrict__ U0,
                                               float* __restrict__ U1,
                                               int plain) {
  const int m0 = blockIdx.x * 64;           // node rows i
  const int n0 = blockIdx.y * 384;          // feature cols
  const int h    = blockIdx.z / KS;
  const int kseg = blockIdx.z % KS;
  const int tid = threadIdx.x;
  const int w = tid >> 6, l = tid & 63;
  const int wu = __builtin_amdgcn_readfirstlane(w);
  // XOR-swizzled [rows][64] tiles (16B-block index ^= row&7)
  __shared__ unsigned short As[64 * 64];    // 8KB
  __shared__ unsigned short Bs[384 * 64];   // 48KB
  const unsigned short* Bg = wht + (size_t)h * OPAD * NN;
  const uint64_t* bmw = bm + (size_t)(m0 + wu * 8) * 128;
  float E1v[8], F1v[8];
#pragma unroll
  for (int r = 0; r < 8; ++r) {
    E1v[r] = e1s[h * NN + m0 + wu * 8 + r];
    F1v[r] = f1s[h * NN + m0 + wu * 8 + r];
  }

  const int kt0 = kseg * (NN / 64 / KS);
  const int ktend = kt0 + NN / 64 / KS;

  f32x4 acc[4][3] = {};

  for (int kt = kt0; kt < ktend; ++kt) {
    const int k0 = kt * 64;
    // e2/f2 FIRST: genA's first use then waits only on these, not the staging drain
    const float e2v = e2s[h * NN + k0 + l];
    const float f2v = f2s[h * NN + k0 + l];
    // stage B (Wh^T panel) async: linear LDS dest, source k-block pre-swizzled
#pragma unroll
    for (int call = 0; call < 6; ++call) {
      int c = call * 512 + tid;             // 16B-chunk index in [0, 3072)
      int row = c >> 3;
      int kb  = c & 7;
      int kbs = kb ^ (row & 7);
      const unsigned short* g = Bg + (size_t)(n0 + row) * NN + k0 + kbs * 8;
      async_ld16(g, &Bs[(size_t)c * 8]);
    }
    // generate A tile: wave handles 8 rows, lane = k within tile
#pragma unroll
    for (int r = 0; r < 8; ++r) {
      uint64_t mrow = bmw[(size_t)r * 128 + kt];
      uint32_t mlo = __builtin_amdgcn_readfirstlane((uint32_t)mrow);
      uint32_t mhi = __builtin_amdgcn_readfirstlane((uint32_t)(mrow >> 32));
      float e = fmaxf(E1v[r] * e2v, F1v[r] * f2v);
      e = selbit(e, mlo, mhi);
      As[(wu * 8 + r) * 64 + (l ^ (r << 3))] = f2bf(e);
    }
    __syncthreads();

#pragma unroll
    for (int ks = 0; ks < 2; ++ks) {
      bf16x8 af[4], bfr[3];
#pragma unroll
      for (int mi = 0; mi < 4; ++mi) {
        int row = mi * 16 + (l & 15);
        af[mi] = *reinterpret_cast<const bf16x8*>(
            &As[row * 64 + (((ks * 4 + (l >> 4)) ^ (row & 7)) * 8)]);
      }
#pragma unroll
      for (int ni = 0; ni < 3; ++ni) {
        int row = w * 48 + ni * 16 + (l & 15);
        bfr[ni] = *reinterpret_cast<const bf16x8*>(
            &Bs[row * 64 + (((ks * 4 + (l >> 4)) ^ (row & 7)) * 8)]);
      }
#pragma unroll
      for (int mi = 0; mi < 4; ++mi)
#pragma unroll
        for (int ni = 0; ni < 3; ++ni)
          acc[mi][ni] = __builtin_amdgcn_mfma_f32_16x16x32_bf16(af[mi], bfr[ni], acc[mi][ni], 0, 0, 0);
    }
    __syncthreads();
  }

  float* Ud = (kseg == 0) ? U0 : U1;
#pragma unroll
  for (int mi = 0; mi < 4; ++mi)
#pragma unroll
    for (int j = 0; j < 4; ++j) {
      int i = m0 + mi * 16 + (l >> 4) * 4 + j;
#pragma unroll
      for (int ni = 0; ni < 3; ++ni) {
        int n = n0 + w * 48 + ni * 16 + (l & 15);
        if (n <= FD) {
          size_t off = ((size_t)h * NN + i) * USTRIDE + n;
          if (plain) Ud[off] = acc[mi][ni][j];
          else       unsafeAtomicAdd(&U0[off], acc[mi][ni][j]);
        }
      }
    }
}

// ---------- y = elu(mean_h U[h][i][o] / U[h][i][FD]) , 2 outputs/thread ----------
__global__ __launch_bounds__(256) void k_final(const float* __restrict__ U0,
                                               const float* __restrict__ U1,
                                               float* __restrict__ y,
                                               int two) {
  int idx = blockIdx.x * 256 + threadIdx.x;      // pair index
  if (idx >= NN * (FD / 2)) return;
  int i = idx / (FD / 2), p = idx - i * (FD / 2);
  int o = p * 2;
  const size_t HS = (size_t)NN * USTRIDE;
  float s0 = 0.f, s1 = 0.f;
#pragma unroll
  for (int h = 0; h < NH; ++h) {
    size_t b = h * HS + (size_t)i * USTRIDE;
    float2 u = *reinterpret_cast<const float2*>(&U0[b + o]);
    float z = U0[b + FD];
    if (two) {
      float2 u2 = *reinterpret_cast<const float2*>(&U1[b + o]);
      u.x += u2.x; u.y += u2.y;
      z += U1[b + FD];
    }
    float zi = 1.0f / z;
    s0 += u.x * zi;
    s1 += u.y * zi;
  }
  s0 *= (1.f / 3.f);
  s1 *= (1.f / 3.f);
  float2 out;
  out.x = s0 > 0.f ? s0 : (expf(s0) - 1.f);
  out.y = s1 > 0.f ? s1 : (expf(s1) - 1.f);
  *reinterpret_cast<float2*>(&y[(size_t)i * FD + o]) = out;
}

extern "C" void kernel_launch(void* const* d_in, const int* in_sizes, int n_in,
                              void* d_out, int out_size, void* d_ws, size_t ws_size,
                              hipStream_t stream) {
  const float* x   = (const float*)d_in[0];
  const int*   adj = (const int*)d_in[1];
  const float* W   = (const float*)d_in[2];
  const float* a   = (const float*)d_in[3];
  float* y = (float*)d_out;

  char* ws = (char*)d_ws;
  size_t off = 0;
  auto alloc = [&](size_t bytes) {
    void* p = ws + off;
    off = (off + bytes + 255) & ~(size_t)255;
    return p;
  };
  unsigned short* xb  = (unsigned short*)alloc((size_t)NN * KPAD * 2);
  unsigned short* wt  = (unsigned short*)alloc((size_t)NH * OPAD * KPAD * 2);
  unsigned short* wht = (unsigned short*)alloc((size_t)NH * OPAD * NN * 2);
  float* e1s = (float*)alloc((size_t)NH * NN * 4);
  float* f1s = (float*)alloc((size_t)NH * NN * 4);
  float* e2s = (float*)alloc((size_t)NH * NN * 4);
  float* f2s = (float*)alloc((size_t)NH * NN * 4);
  uint64_t* bm = (uint64_t*)alloc((size_t)NN * 128 * 8);
  float* U0 = (float*)alloc((size_t)NH * NN * USTRIDE * 4);
  float* a1acc = (float*)alloc((size_t)NH * NN * 4);
  float* a2acc = (float*)alloc((size_t)NH * NN * 4);
  const size_t usize = (size_t)NH * NN * USTRIDE * 4;
  bool two = (ws_size >= off + usize + 256);
  float* U1 = two ? (float*)alloc(usize) : U0;
  (void)in_sizes; (void)n_in; (void)out_size;

  if (!two) hipMemsetAsync(U0, 0, usize, stream);

  const int cast_total = NN * KPAD / 4 + NH * OPAD * KPAD + 2 * NH * NN / 4;
  k_cast<<<(cast_total + 255) / 256, 256, 0, stream>>>(x, W, xb, wt, (float4*)a1acc);
  k_gw_pack<<<GW_BLOCKS + PK_BLOCKS, 512, 0, stream>>>(wt, xb, a, wht, a1acc, a2acc,
                                                       (const int4*)adj, bm);
  k_exp<<<(NH * NN + 255) / 256, 256, 0, stream>>>(a1acc, a2acc, e1s, f1s, e2s, f2s);
  k_pv<<<dim3(NN / 64, 2, NH * KS), 512, 0, stream>>>(wht, e1s, f1s, e2s, f2s, bm,
                                                      U0, U1, two ? 1 : 0);
  k_final<<<(NN * (FD / 2) + 255) / 256, 256, 0, stream>>>(U0, U1, y, two ? 1 : 0);
}

// Round 17
// 542.372 us; speedup vs baseline: 1.0245x; 1.0245x over previous
//
#include <hip/hip_runtime.h>
#include <hip/hip_bf16.h>
#include <stdint.h>

#define NN 8192
#define FD 690
#define NH 3
#define KPAD 704   // F_IN padded to mult of 64
#define OPAD 768   // F_OUT padded to mult of 128 (row FD holds constant 1 -> Z column)
#define USTRIDE 704
#define KS 2       // K-split factor for k_pv
#define LOG2E 1.4426950408889634f

typedef __attribute__((ext_vector_type(8))) short bf16x8;
typedef __attribute__((ext_vector_type(4))) float f32x4;

typedef __attribute__((address_space(1))) const void gas_t;
typedef __attribute__((address_space(3))) void las_t;

__device__ __forceinline__ void async_ld16(const void* g, void* l) {
  __builtin_amdgcn_global_load_lds((gas_t*)g, (las_t*)l, 16, 0, 0);
}

__device__ __forceinline__ float bf2f(unsigned short u) {
  return __uint_as_float(((unsigned int)u) << 16);
}
__device__ __forceinline__ unsigned short f2bf(float f) {
  __hip_bfloat16 h = __float2bfloat16(f);
  return *reinterpret_cast<unsigned short*>(&h);
}
// r = bit[lane] of (hi:lo) ? e : 0 — mask forced scalar via readfirstlane upstream
__device__ __forceinline__ float selbit(float e, uint32_t lo, uint32_t hi) {
  uint64_t m = ((uint64_t)hi << 32) | lo;
  float r;
  asm("v_cndmask_b32 %0, 0, %1, %2" : "=v"(r) : "v"(e), "s"(m));
  return r;
}

// ---------- fused cast / pad / zero-acc (xb vec4, wt scalar, acc zeroing) ----------
__global__ __launch_bounds__(256) void k_cast(const float* __restrict__ x,
                                              const float* __restrict__ W,
                                              unsigned short* __restrict__ xb,
                                              unsigned short* __restrict__ wt,
                                              float4* __restrict__ accz) {
  int q = blockIdx.x * 256 + threadIdx.x;
  const int XQ = NN * KPAD / 4;
  if (q < XQ) {
    int idx = q * 4;
    int n = idx / KPAD, f = idx - n * KPAD;   // f mult of 4
    uint2 out;
    if (f + 3 < FD) {
      const float* xp = &x[(size_t)n * FD + f];
      float2 a = *reinterpret_cast<const float2*>(xp);
      float2 b = *reinterpret_cast<const float2*>(xp + 2);
      out.x = (uint32_t)f2bf(a.x) | ((uint32_t)f2bf(a.y) << 16);
      out.y = (uint32_t)f2bf(b.x) | ((uint32_t)f2bf(b.y) << 16);
    } else {
      unsigned short e[4];
#pragma unroll
      for (int t = 0; t < 4; ++t) {
        int ff = f + t;
        e[t] = (ff < FD) ? f2bf(x[(size_t)n * FD + ff]) : 0;
      }
      out.x = (uint32_t)e[0] | ((uint32_t)e[1] << 16);
      out.y = (uint32_t)e[2] | ((uint32_t)e[3] << 16);
    }
    *reinterpret_cast<uint2*>(&xb[idx]) = out;
    return;
  }
  int idx = q - XQ;
  if (idx < NH * OPAD * KPAD) {
    int h = idx / (OPAD * KPAD);
    int rem = idx - h * OPAD * KPAD;
    int o = rem / KPAD, f = rem - o * KPAD;
    float v = (o < FD && f < FD) ? W[((size_t)h * FD + f) * FD + o] : 0.f;
    wt[idx] = f2bf(v);
    return;
  }
  idx -= NH * OPAD * KPAD;
  if (idx < 2 * NH * NN / 4) {
    float4 z; z.x = 0.f; z.y = 0.f; z.z = 0.f; z.w = 0.f;
    accz[idx] = z;
  }
}

// ---------- adjacency -> bitmask, int4 loads + shfl nibble tree ----------
__global__ __launch_bounds__(256) void k_pack(const int4* __restrict__ adj4,
                                              uint64_t* __restrict__ bm) {
  int gw = (blockIdx.x * 256 + threadIdx.x) >> 6;   // wave id; NN*32 total
  int lane = threadIdx.x & 63;
  int i = gw >> 5, seg = gw & 31;                   // seg: 256 cols = 4 mask words
  int4 v = adj4[(size_t)i * (NN / 4) + seg * 64 + lane];
  uint32_t nib = (uint32_t)(v.x > 0) | ((uint32_t)(v.y > 0) << 1)
               | ((uint32_t)(v.z > 0) << 2) | ((uint32_t)(v.w > 0) << 3);
  nib |= __shfl_xor(nib, 1) << 4;     // 8 bits valid at lane%2==0
  nib |= __shfl_xor(nib, 2) << 8;     // 16 bits valid at lane%4==0
  nib |= __shfl_xor(nib, 4) << 16;    // 32 bits valid at lane%8==0
  uint32_t hi = __shfl_xor(nib, 8);   // other half's 32 bits
  if ((lane & 15) == 0)
    bm[(size_t)i * 128 + seg * 4 + (lane >> 4)] = (uint64_t)nib | ((uint64_t)hi << 32);
}

// ---------- WhT[h][o][n] = sum_f x[n][f] W[h][f][o]  (bf16 out; row FD = 1.0) ----------
// Epilogue additionally folds the a1/a2 score projections (f32, atomics).
__global__ __launch_bounds__(512) void k_gemm_wht(const unsigned short* __restrict__ wt,
                                                  const unsigned short* __restrict__ xb,
                                                  const float* __restrict__ a,
                                                  unsigned short* __restrict__ wht,
                                                  float* __restrict__ a1acc,
                                                  float* __restrict__ a2acc) {
  const int m0 = blockIdx.x * 128;   // o
  const int n0 = blockIdx.y * 256;   // node
  const int h  = blockIdx.z;
  const int tid = threadIdx.x;
  const int w = tid >> 6, l = tid & 63;
  const int wm = w >> 2, wn = w & 3;
  __shared__ unsigned short As[128 * 64];
  __shared__ unsigned short Bs[256 * 64];
  const unsigned short* Ag = wt + (size_t)h * OPAD * KPAD;
  f32x4 acc[4][4] = {};
  for (int kt = 0; kt < KPAD / 64; ++kt) {
    const int k0 = kt * 64;
#pragma unroll
    for (int r = 0; r < 2; ++r) {
      const unsigned short* g = Ag + (size_t)(m0 + r * 64 + w * 8 + (l >> 3)) * KPAD + k0 + (l & 7) * 8;
      async_ld16(g, &As[(r * 64 + w * 8) * 64]);
    }
#pragma unroll
    for (int r = 0; r < 4; ++r) {
      const unsigned short* g = xb + (size_t)(n0 + r * 64 + w * 8 + (l >> 3)) * KPAD + k0 + (l & 7) * 8;
      async_ld16(g, &Bs[(r * 64 + w * 8) * 64]);
    }
    __syncthreads();
#pragma unroll
    for (int ks = 0; ks < 2; ++ks) {
      bf16x8 af[4], bfr[4];
#pragma unroll
      for (int mi = 0; mi < 4; ++mi)
        af[mi] = *reinterpret_cast<const bf16x8*>(
            &As[(wm * 64 + mi * 16 + (l & 15)) * 64 + ks * 32 + (l >> 4) * 8]);
#pragma unroll
      for (int ni = 0; ni < 4; ++ni)
        bfr[ni] = *reinterpret_cast<const bf16x8*>(
            &Bs[(wn * 64 + ni * 16 + (l & 15)) * 64 + ks * 32 + (l >> 4) * 8]);
#pragma unroll
      for (int mi = 0; mi < 4; ++mi)
#pragma unroll
        for (int ni = 0; ni < 4; ++ni)
          acc[mi][ni] = __builtin_amdgcn_mfma_f32_16x16x32_bf16(af[mi], bfr[ni], acc[mi][ni], 0, 0, 0);
    }
    __syncthreads();
  }
  unsigned short* Wh = wht + (size_t)h * OPAD * NN;
#pragma unroll
  for (int mi = 0; mi < 4; ++mi)
#pragma unroll
    for (int j = 0; j < 4; ++j) {
      int o = m0 + wm * 64 + mi * 16 + (l >> 4) * 4 + j;
#pragma unroll
      for (int ni = 0; ni < 4; ++ni) {
        int n = n0 + wn * 64 + ni * 16 + (l & 15);
        float val = (o == FD) ? 1.0f : acc[mi][ni][j];  // pad rows are exactly 0; row FD = ones
        Wh[(size_t)o * NN + n] = f2bf(val);
      }
    }
  // ---- a1/a2 partial projections (f32 acc, per-(n) atomics) ----
  const float* ap1 = a + h * 2 * FD;
  const float* ap2 = ap1 + FD;
  float av1[4][4], av2[4][4];
#pragma unroll
  for (int mi = 0; mi < 4; ++mi)
#pragma unroll
    for (int j = 0; j < 4; ++j) {
      int o = m0 + wm * 64 + mi * 16 + (l >> 4) * 4 + j;
      bool ok = (o < FD);
      av1[mi][j] = ok ? ap1[o] : 0.f;
      av2[mi][j] = ok ? ap2[o] : 0.f;
    }
#pragma unroll
  for (int ni = 0; ni < 4; ++ni) {
    float p1 = 0.f, p2 = 0.f;
#pragma unroll
    for (int mi = 0; mi < 4; ++mi)
#pragma unroll
      for (int j = 0; j < 4; ++j) {
        p1 += acc[mi][ni][j] * av1[mi][j];
        p2 += acc[mi][ni][j] * av2[mi][j];
      }
    int n = n0 + wn * 64 + ni * 16 + (l & 15);
    unsafeAtomicAdd(&a1acc[h * NN + n], p1);
    unsafeAtomicAdd(&a2acc[h * NN + n], p2);
  }
}

// ---------- E/F factors from accumulated a1/a2 ----------
__global__ __launch_bounds__(256) void k_exp(const float* __restrict__ a1acc,
                                             const float* __restrict__ a2acc,
                                             float* __restrict__ e1s, float* __restrict__ f1s,
                                             float* __restrict__ e2s, float* __restrict__ f2s) {
  int i = blockIdx.x * 256 + threadIdx.x;
  if (i >= NH * NN) return;
  float s1 = a1acc[i] * LOG2E, s2 = a2acc[i] * LOG2E;
  e1s[i] = exp2f(s1);
  f1s[i] = exp2f(0.2f * s1);
  e2s[i] = exp2f(s2);
  f2s[i] = exp2f(0.2f * s2);
}

// ---------- PV: U{0,1}[h][i][n] (+)= sum_{j in kseg} w_ij WhT[n][j] ; column FD = Z ----------
// w_ij = max(E1_i*E2_j, F1_i*F2_j)  (== exp2(log2e*lrelu(a1_i+a2_j)), exp2 monotone)
// r7/r15 measured-optimum loop (370us, VGPR 56, 0 bank conflicts), untouched.
// Epilogue: plain==1 -> kseg writes its own buffer (no RMW, no memset);
//           plain==0 -> atomicAdd into U0 (fallback when ws is small).
__global__ __launch_bounds__(512, 4) void k_pv(const unsigned short* __restrict__ wht,
                                               const float* __restrict__ e1s,
                                               const float* __restrict__ f1s,
                                               const float* __restrict__ e2s,
                                               const float* __restrict__ f2s,
                                               const uint64_t* __restrict__ bm,
                                               float* __restrict__ U0,
                                               float* __restrict__ U1,
                                               int plain) {
  const int m0 = blockIdx.x * 64;           // node rows i
  const int n0 = blockIdx.y * 384;          // feature cols
  const int h    = blockIdx.z / KS;
  const int kseg = blockIdx.z % KS;
  const int tid = threadIdx.x;
  const int w = tid >> 6, l = tid & 63;
  const int wu = __builtin_amdgcn_readfirstlane(w);
  // XOR-swizzled [rows][64] tiles (16B-block index ^= row&7)
  __shared__ unsigned short As[64 * 64];    // 8KB
  __shared__ unsigned short Bs[384 * 64];   // 48KB
  const unsigned short* Bg = wht + (size_t)h * OPAD * NN;
  const uint64_t* bmw = bm + (size_t)(m0 + wu * 8) * 128;
  float E1v[8], F1v[8];
#pragma unroll
  for (int r = 0; r < 8; ++r) {
    E1v[r] = e1s[h * NN + m0 + wu * 8 + r];
    F1v[r] = f1s[h * NN + m0 + wu * 8 + r];
  }

  const int kt0 = kseg * (NN / 64 / KS);
  const int ktend = kt0 + NN / 64 / KS;

  f32x4 acc[4][3] = {};

  for (int kt = kt0; kt < ktend; ++kt) {
    const int k0 = kt * 64;
    // e2/f2 FIRST: genA's first use then waits only on these, not the staging drain
    const float e2v = e2s[h * NN + k0 + l];
    const float f2v = f2s[h * NN + k0 + l];
    // stage B (Wh^T panel) async: linear LDS dest, source k-block pre-swizzled
#pragma unroll
    for (int call = 0; call < 6; ++call) {
      int c = call * 512 + tid;             // 16B-chunk index in [0, 3072)
      int row = c >> 3;
      int kb  = c & 7;
      int kbs = kb ^ (row & 7);
      const unsigned short* g = Bg + (size_t)(n0 + row) * NN + k0 + kbs * 8;
      async_ld16(g, &Bs[(size_t)c * 8]);
    }
    // generate A tile: wave handles 8 rows, lane = k within tile
#pragma unroll
    for (int r = 0; r < 8; ++r) {
      uint64_t mrow = bmw[(size_t)r * 128 + kt];
      uint32_t mlo = __builtin_amdgcn_readfirstlane((uint32_t)mrow);
      uint32_t mhi = __builtin_amdgcn_readfirstlane((uint32_t)(mrow >> 32));
      float e = fmaxf(E1v[r] * e2v, F1v[r] * f2v);
      e = selbit(e, mlo, mhi);
      As[(wu * 8 + r) * 64 + (l ^ (r << 3))] = f2bf(e);
    }
    __syncthreads();

#pragma unroll
    for (int ks = 0; ks < 2; ++ks) {
      bf16x8 af[4], bfr[3];
#pragma unroll
      for (int mi = 0; mi < 4; ++mi) {
        int row = mi * 16 + (l & 15);
        af[mi] = *reinterpret_cast<const bf16x8*>(
            &As[row * 64 + (((ks * 4 + (l >> 4)) ^ (row & 7)) * 8)]);
      }
#pragma unroll
      for (int ni = 0; ni < 3; ++ni) {
        int row = w * 48 + ni * 16 + (l & 15);
        bfr[ni] = *reinterpret_cast<const bf16x8*>(
            &Bs[row * 64 + (((ks * 4 + (l >> 4)) ^ (row & 7)) * 8)]);
      }
#pragma unroll
      for (int mi = 0; mi < 4; ++mi)
#pragma unroll
        for (int ni = 0; ni < 3; ++ni)
          acc[mi][ni] = __builtin_amdgcn_mfma_f32_16x16x32_bf16(af[mi], bfr[ni], acc[mi][ni], 0, 0, 0);
    }
    __syncthreads();
  }

  float* Ud = (kseg == 0) ? U0 : U1;
#pragma unroll
  for (int mi = 0; mi < 4; ++mi)
#pragma unroll
    for (int j = 0; j < 4; ++j) {
      int i = m0 + mi * 16 + (l >> 4) * 4 + j;
#pragma unroll
      for (int ni = 0; ni < 3; ++ni) {
        int n = n0 + w * 48 + ni * 16 + (l & 15);
        if (n <= FD) {
          size_t off = ((size_t)h * NN + i) * USTRIDE + n;
          if (plain) Ud[off] = acc[mi][ni][j];
          else       unsafeAtomicAdd(&U0[off], acc[mi][ni][j]);
        }
      }
    }
}

// ---------- y = elu(mean_h U[h][i][o] / U[h][i][FD]) , 2 outputs/thread ----------
__global__ __launch_bounds__(256) void k_final(const float* __restrict__ U0,
                                               const float* __restrict__ U1,
                                               float* __restrict__ y,
                                               int two) {
  int idx = blockIdx.x * 256 + threadIdx.x;      // pair index
  if (idx >= NN * (FD / 2)) return;
  int i = idx / (FD / 2), p = idx - i * (FD / 2);
  int o = p * 2;
  const size_t HS = (size_t)NN * USTRIDE;
  float s0 = 0.f, s1 = 0.f;
#pragma unroll
  for (int h = 0; h < NH; ++h) {
    size_t b = h * HS + (size_t)i * USTRIDE;
    float2 u = *reinterpret_cast<const float2*>(&U0[b + o]);
    float z = U0[b + FD];
    if (two) {
      float2 u2 = *reinterpret_cast<const float2*>(&U1[b + o]);
      u.x += u2.x; u.y += u2.y;
      z += U1[b + FD];
    }
    float zi = 1.0f / z;
    s0 += u.x * zi;
    s1 += u.y * zi;
  }
  s0 *= (1.f / 3.f);
  s1 *= (1.f / 3.f);
  float2 out;
  out.x = s0 > 0.f ? s0 : (expf(s0) - 1.f);
  out.y = s1 > 0.f ? s1 : (expf(s1) - 1.f);
  *reinterpret_cast<float2*>(&y[(size_t)i * FD + o]) = out;
}

extern "C" void kernel_launch(void* const* d_in, const int* in_sizes, int n_in,
                              void* d_out, int out_size, void* d_ws, size_t ws_size,
                              hipStream_t stream) {
  const float* x   = (const float*)d_in[0];
  const int*   adj = (const int*)d_in[1];
  const float* W   = (const float*)d_in[2];
  const float* a   = (const float*)d_in[3];
  float* y = (float*)d_out;

  char* ws = (char*)d_ws;
  size_t off = 0;
  auto alloc = [&](size_t bytes) {
    void* p = ws + off;
    off = (off + bytes + 255) & ~(size_t)255;
    return p;
  };
  unsigned short* xb  = (unsigned short*)alloc((size_t)NN * KPAD * 2);
  unsigned short* wt  = (unsigned short*)alloc((size_t)NH * OPAD * KPAD * 2);
  unsigned short* wht = (unsigned short*)alloc((size_t)NH * OPAD * NN * 2);
  float* e1s = (float*)alloc((size_t)NH * NN * 4);
  float* f1s = (float*)alloc((size_t)NH * NN * 4);
  float* e2s = (float*)alloc((size_t)NH * NN * 4);
  float* f2s = (float*)alloc((size_t)NH * NN * 4);
  uint64_t* bm = (uint64_t*)alloc((size_t)NN * 128 * 8);
  float* U0 = (float*)alloc((size_t)NH * NN * USTRIDE * 4);
  float* a1acc = (float*)alloc((size_t)NH * NN * 4);
  float* a2acc = (float*)alloc((size_t)NH * NN * 4);
  const size_t usize = (size_t)NH * NN * USTRIDE * 4;
  bool two = (ws_size >= off + usize + 256);
  float* U1 = two ? (float*)alloc(usize) : U0;
  (void)in_sizes; (void)n_in; (void)out_size;

  if (!two) hipMemsetAsync(U0, 0, usize, stream);

  const int cast_total = NN * KPAD / 4 + NH * OPAD * KPAD + 2 * NH * NN / 4;
  k_cast<<<(cast_total + 255) / 256, 256, 0, stream>>>(x, W, xb, wt, (float4*)a1acc);
  k_pack<<<NN * 32 * 64 / 256, 256, 0, stream>>>((const int4*)adj, bm);
  k_gemm_wht<<<dim3(OPAD / 128, NN / 256, NH), 512, 0, stream>>>(wt, xb, a, wht, a1acc, a2acc);
  k_exp<<<(NH * NN + 255) / 256, 256, 0, stream>>>(a1acc, a2acc, e1s, f1s, e2s, f2s);
  k_pv<<<dim3(NN / 64, 2, NH * KS), 512, 0, stream>>>(wht, e1s, f1s, e2s, f2s, bm,
                                                      U0, U1, two ? 1 : 0);
  k_final<<<(NN * (FD / 2) + 255) / 256, 256, 0, stream>>>(U0, U1, y, two ? 1 : 0);
}